// Round 2
// baseline (3137.497 us; speedup 1.0000x reference)
//
#include <hip/hip_runtime.h>
#include <hip/hip_bf16.h>
#include <stdint.h>

// ---------------------------------------------------------------------------
// LiGRU (3x bidirectional, shared-weight flip-and-stack) + FC, MI355X gfx950.
// B=64, T=500, D_IN=89, H=512, G=2H=1024, OUT=61.  Stacked rows R=128.
// ---------------------------------------------------------------------------

typedef __attribute__((ext_vector_type(8))) short bf16x8;     // 8 x bf16
typedef __attribute__((ext_vector_type(4))) float f32x4;
typedef __attribute__((ext_vector_type(4))) unsigned short u16x4;
typedef __attribute__((ext_vector_type(2))) unsigned int u32x2;

#define AS1 __attribute__((address_space(1)))
#define AS3 __attribute__((address_space(3)))
#define GLDS16(g, s)                                                           \
  __builtin_amdgcn_global_load_lds((const AS1 void*)(g), (AS3 void*)(s), 16, 0, 0)

__device__ __forceinline__ unsigned short f2bf(float f) {
  unsigned u = __builtin_bit_cast(unsigned, f);
  u += 0x7fffu + ((u >> 16) & 1u);          // RNE
  return (unsigned short)(u >> 16);
}
__device__ __forceinline__ float bf2f(unsigned short s) {
  unsigned u = ((unsigned)s) << 16;
  return __builtin_bit_cast(float, u);
}

// --------------------------- fp32 -> bf16 convert ---------------------------
__global__ void k_f2b(unsigned short* __restrict__ dst, const float* __restrict__ src,
                      int dstCols, int srcStride, int srcOff, int copyCols) {
  long r = blockIdx.x;
  const float* s = src + r * (long)srcStride + srcOff;
  unsigned short* d = dst + r * (long)dstCols;
  for (int c = threadIdx.x; c < dstCols; c += blockDim.x)
    d[c] = (c < copyCols) ? f2bf(s[c]) : (unsigned short)0;
}

// bar: 3 scans x 1024 ints ([0..511]=flags (8 rg x 64), [512..1023]=xcc pub)
__global__ void k_init(int* __restrict__ bar, unsigned short* __restrict__ fcPad) {
  int t = threadIdx.x;
  for (int i = t; i < 3 * 1024; i += 256) bar[i] = 0;
  for (int i = t; i < 6 * 512; i += 256) fcPad[i] = 0;
}

// ------------------------------- bf16 GEMM ----------------------------------
// C[M,N] = A[M,K] * Bt[N,K]^T.  128x128 tile, BK=32, 4 waves (2x2), each 64x64.
template <int OUTBF>
__global__ __launch_bounds__(256, 2) void k_gemm(
    const unsigned short* __restrict__ A, const unsigned short* __restrict__ Bt,
    void* __restrict__ C, int K, int ldc) {
  __shared__ __align__(16) unsigned short As[128 * 32];
  __shared__ __align__(16) unsigned short Bs[128 * 32];
  const int tid = threadIdx.x;
  const int w = tid >> 6, l = tid & 63;
  const int wm = w >> 1, wn = w & 1;
  const int l15 = l & 15, l4 = l >> 4;
  const long m0 = (long)blockIdx.x * 128;
  const long n0 = (long)blockIdx.y * 128;
  const int lr = l >> 2, lk = (l & 3) * 8;

  f32x4 acc[4][4] = {};

  for (int k0 = 0; k0 < K; k0 += 32) {
    __syncthreads();
#pragma unroll
    for (int i = 0; i < 2; ++i) {
      const int ra = w * 32 + i * 16;
      const unsigned short* ga = A + (m0 + ra + lr) * K + k0 + lk;
      const unsigned short* gb = Bt + (n0 + ra + lr) * K + k0 + lk;
      GLDS16(ga, As + ra * 32);
      GLDS16(gb, Bs + ra * 32);
    }
    asm volatile("s_waitcnt vmcnt(0)" ::: "memory");
    __syncthreads();
    bf16x8 af[4], bfv[4];
#pragma unroll
    for (int mt = 0; mt < 4; ++mt)
      af[mt] = *(const bf16x8*)(As + (wm * 64 + mt * 16 + l15) * 32 + l4 * 8);
#pragma unroll
    for (int nt = 0; nt < 4; ++nt)
      bfv[nt] = *(const bf16x8*)(Bs + (wn * 64 + nt * 16 + l15) * 32 + l4 * 8);
#pragma unroll
    for (int mt = 0; mt < 4; ++mt)
#pragma unroll
      for (int nt = 0; nt < 4; ++nt)
        acc[mt][nt] =
            __builtin_amdgcn_mfma_f32_16x16x32_bf16(af[mt], bfv[nt], acc[mt][nt], 0, 0, 0);
  }
  const int rr = l4 * 4, cc = l15;
#pragma unroll
  for (int mt = 0; mt < 4; ++mt)
#pragma unroll
    for (int nt = 0; nt < 4; ++nt) {
      const long col = n0 + wn * 64 + nt * 16 + cc;
#pragma unroll
      for (int j = 0; j < 4; ++j) {
        const long row = m0 + wm * 64 + mt * 16 + rr + j;
        if (OUTBF)
          ((unsigned short*)C)[row * ldc + col] = f2bf(acc[mt][nt][j]);
        else
          ((float*)C)[row * ldc + col] = acc[mt][nt][j];
      }
    }
}

// ------------------------------- scan core ----------------------------------
// Operand-swapped MFMA: G^T = mfma(U_frag [16 gatecols x K], h_frag [16 tok x K]).
// Lane l owns token l15, h cols 16*ws + 4*l4 + j (j=0..3).
// Exchange: hx ring of 4 slots, each [8 rg][32 ws][16 tok][16 col] bf16.
// Flags: flag[rg][ws] = t+1 after h(t) tile stored & drained (vmcnt(0)).
//
// Addressing: all hot-loop VMEM is saddr-form inline asm (uniform SGPR base
// advanced by one scalar add per step; per-lane 32-bit voffsets precomputed,
// per-kt offsets in the 13-bit immediate) -> zero per-step vector address math.
//
// Release protocol (UNCHANGED from the verified baseline): tile stores ->
// s_waitcnt vmcnt(0) with a STORES-ONLY queue -> flag -> hs store -> PQ issue.
// (A counted vmcnt across a mixed store/load queue is NOT safe: store-ack vs
// load retirement order is not guaranteed; an early-retiring PQ load can
// satisfy the count with the tile store still in flight -> early flag ->
// siblings read unwritten hx -> NaN.  Verified the hard way in round 0.)
//
// Split h-load wait: queue at the h-load point is [hs store][PQ loads][16 H
// loads].  vmcnt(8) guarantees hv[0..7] and the PQ regs are ready under the
// only assumption that LOADS retire in order among themselves (m135), for ANY
// store-retire order: any <=8-outstanding set is a suffix of the load order
// plus possibly the hs store.  First 16 MFMAs then overlap the tail 8 loads.
template <int PAIRED, bool FAST>
__device__ __forceinline__ void scan_body(
    const int rg, const int ws, const int l, const int l15, const int l4,
    const int pl, const bf16x8* Ua, const bf16x8* Uz,
    const unsigned short* __restrict__ PQ, unsigned short* __restrict__ hs,
    unsigned short* __restrict__ hx, int* __restrict__ rgflags,
    int* __restrict__ myflag) {
  float h_own[4] = {0.f, 0.f, 0.f, 0.f};
  const int gc = 16 * ws + 4 * l4;          // absolute gate/h col base
  const int r = rg * 16 + l15;              // absolute token row

  // ---- saddr-form addressing: uniform SGPR bases + precomputed lane voffs ----
  // h-tile loads: slot base = hx + slot*131072 + rg*16384 bytes;
  // per-kt byte offset = kt*1024 + (l4>>1)*512 + l15*32 + (l4&1)*16.
  const unsigned voffG0 = (unsigned)((l4 >> 1) * 512 + l15 * 32 + (l4 & 1) * 16);
  const unsigned voffG1 = voffG0 + 4096u;
  const unsigned voffG2 = voffG0 + 8192u;
  const unsigned voffG3 = voffG0 + 12288u;
  // tile store: base = hx + slot*131072 + rg*16384 + ws*512; lane off below.
  const unsigned voffT = (unsigned)(l15 * 32 + l4 * 8);
  const unsigned long long hxB =
      (unsigned long long)(uintptr_t)hx + (unsigned)(rg * 16384);

  // PQ stream 1: row rr1 at time (fwd1 ? t : 499-t); both uniform per wave.
  const int fwd1 = (PAIRED || rg < 4) ? 1 : 0;
  const unsigned voffP1 =
      (unsigned)(fwd1 ? r : r - 64) * 1024000u + (unsigned)(gc * 2);
  unsigned long long sP1 =
      (unsigned long long)(uintptr_t)PQ + (fwd1 ? 0u : 1021952u);
  const long long dP1 = fwd1 ? 2048 : -2048;
  // PQ stream 2 (PAIRED only): row (r+64)&127 at time 499-t.
  const unsigned voffP2 =
      (unsigned)((r + 64) & 127) * 1024000u + (unsigned)(gc * 2);
  unsigned long long sP2 = (unsigned long long)(uintptr_t)PQ + 1021952u;
  // hs store: byte addr = hs + r*512000 + t*1024 + gc*2.
  const unsigned voffH = (unsigned)r * 512000u + (unsigned)(gc * 2);
  unsigned long long sH = (unsigned long long)(uintptr_t)hs;

  u16x4 ra1 = {0, 0, 0, 0}, rz1 = {0, 0, 0, 0};
  u16x4 ra2 = {0, 0, 0, 0}, rz2 = {0, 0, 0, 0};

#define PQ_ISSUE()                                                             \
  do {                                                                         \
    asm volatile("global_load_dwordx2 %0, %1, %2 nt"                           \
                 : "=v"(ra1) : "v"(voffP1), "s"(sP1));                         \
    asm volatile("global_load_dwordx2 %0, %1, %2 offset:1024 nt"               \
                 : "=v"(rz1) : "v"(voffP1), "s"(sP1));                         \
    if (PAIRED) {                                                              \
      asm volatile("global_load_dwordx2 %0, %1, %2 nt"                         \
                   : "=v"(ra2) : "v"(voffP2), "s"(sP2));                       \
      asm volatile("global_load_dwordx2 %0, %1, %2 offset:1024 nt"             \
                   : "=v"(rz2) : "v"(voffP2), "s"(sP2));                       \
    }                                                                          \
  } while (0)

  // prologue: PQ(0) must be complete before the t=0 update (asm loads are not
  // compiler-tracked -> explicit drain + fence).
  PQ_ISSUE();
  sP1 += dP1;
  sP2 -= 2048;
  asm volatile("s_waitcnt vmcnt(0)" ::: "memory");
  __builtin_amdgcn_sched_barrier(0);

  for (int t = 0; t < 500; ++t) {
    f32x4 a0 = {0.f, 0.f, 0.f, 0.f}, a1 = {0.f, 0.f, 0.f, 0.f};
    f32x4 z0 = {0.f, 0.f, 0.f, 0.f}, z1 = {0.f, 0.f, 0.f, 0.f};
    if (t > 0) {
      // ---- wait: all 32 sibling waves finished step t-1 ----
      int spins = 0;
      for (;;) {
        int f = FAST ? __hip_atomic_load(rgflags + pl, __ATOMIC_RELAXED,
                                         __HIP_MEMORY_SCOPE_AGENT)
                     : __hip_atomic_load(rgflags + pl, __ATOMIC_ACQUIRE,
                                         __HIP_MEMORY_SCOPE_AGENT);
        if (__all(f >= t)) break;
        if (++spins > (1 << 20)) break;  // loud-failure insurance
      }
      asm volatile("" ::: "memory");
      // ---- load h(t-1) tiles from hx ring (saddr-form, L1-bypassing) ----
      const unsigned long long sbSlot =
          hxB + (unsigned)(((t - 1) & 3) * 131072);
      bf16x8 hv[16];
#define HLOAD(idx, vg, IMMSTR)                                                 \
      do {                                                                     \
        if (FAST)                                                              \
          asm volatile("global_load_dwordx4 %0, %1, %2 offset:" IMMSTR " sc0"  \
                       : "=v"(hv[idx]) : "v"(vg), "s"(sbSlot));                \
        else                                                                   \
          asm volatile("global_load_dwordx4 %0, %1, %2 offset:" IMMSTR         \
                       " sc0 sc1"                                              \
                       : "=v"(hv[idx]) : "v"(vg), "s"(sbSlot));                \
      } while (0)
      HLOAD(0, voffG0, "0");     HLOAD(1, voffG0, "1024");
      HLOAD(2, voffG0, "2048");  HLOAD(3, voffG0, "3072");
      HLOAD(4, voffG1, "0");     HLOAD(5, voffG1, "1024");
      HLOAD(6, voffG1, "2048");  HLOAD(7, voffG1, "3072");
      HLOAD(8, voffG2, "0");     HLOAD(9, voffG2, "1024");
      HLOAD(10, voffG2, "2048"); HLOAD(11, voffG2, "3072");
      HLOAD(12, voffG3, "0");    HLOAD(13, voffG3, "1024");
      HLOAD(14, voffG3, "2048"); HLOAD(15, voffG3, "3072");
#undef HLOAD
      // ---- split wait: first 8 tiles -> 16 MFMAs overlap the tail loads ----
      if (FAST)
        asm volatile("s_waitcnt vmcnt(8)" ::: "memory");
      else
        asm volatile("s_waitcnt vmcnt(0)" ::: "memory");
      __builtin_amdgcn_sched_barrier(0);
#pragma unroll
      for (int kt = 0; kt < 8; kt += 2) {
        a0 = __builtin_amdgcn_mfma_f32_16x16x32_bf16(Ua[kt], hv[kt], a0, 0, 0, 0);
        z0 = __builtin_amdgcn_mfma_f32_16x16x32_bf16(Uz[kt], hv[kt], z0, 0, 0, 0);
        a1 = __builtin_amdgcn_mfma_f32_16x16x32_bf16(Ua[kt + 1], hv[kt + 1], a1, 0, 0, 0);
        z1 = __builtin_amdgcn_mfma_f32_16x16x32_bf16(Uz[kt + 1], hv[kt + 1], z1, 0, 0, 0);
      }
      if (FAST) {
        asm volatile("s_waitcnt vmcnt(0)" ::: "memory");
        __builtin_amdgcn_sched_barrier(0);
      }
#pragma unroll
      for (int kt = 8; kt < 16; kt += 2) {
        a0 = __builtin_amdgcn_mfma_f32_16x16x32_bf16(Ua[kt], hv[kt], a0, 0, 0, 0);
        z0 = __builtin_amdgcn_mfma_f32_16x16x32_bf16(Uz[kt], hv[kt], z0, 0, 0, 0);
        a1 = __builtin_amdgcn_mfma_f32_16x16x32_bf16(Ua[kt + 1], hv[kt + 1], a1, 0, 0, 0);
        z1 = __builtin_amdgcn_mfma_f32_16x16x32_bf16(Uz[kt + 1], hv[kt + 1], z1, 0, 0, 0);
      }
    }
    // ---- LiGRU update (fp32); lane holds token l15, cols gc..gc+3 ----
    auto upd = [&](int j) {
      float A = a0[j] + a1[j] + bf2f(ra1[j]);
      float Z = z0[j] + z1[j] + bf2f(rz1[j]);
      if (PAIRED) {
        A += bf2f(ra2[j]);
        Z += bf2f(rz2[j]);
      }
      const float zs = 1.f / (1.f + __expf(-Z));                 // sigmoid
      const float e2 = __expf(-2.f * fabsf(A));
      const float th = copysignf((1.f - e2) / (1.f + e2), A);    // tanh
      h_own[j] = zs * h_own[j] + (1.f - zs) * th;
    };
    const unsigned long long sT =
        hxB + (unsigned)((t & 3) * 131072 + ws * 512);
    upd(0);
    upd(1);
    const unsigned d01 =
        (unsigned)f2bf(h_own[0]) | ((unsigned)f2bf(h_own[1]) << 16);
    if (FAST) {
      // first half of the tile ships while j=2,3 transcendentals run
      asm volatile("global_store_dword %0, %1, %2"
                   :: "v"(voffT), "v"(d01), "s"(sT) : "memory");
    }
    upd(2);
    upd(3);
    const unsigned d23 =
        (unsigned)f2bf(h_own[2]) | ((unsigned)f2bf(h_own[3]) << 16);
    if (FAST) {
      asm volatile("global_store_dword %0, %1, %2 offset:4"
                   :: "v"(voffT), "v"(d23), "s"(sT) : "memory");
      // release: STORES-ONLY queue -> full drain -> flag.
      asm volatile("s_waitcnt vmcnt(0)" ::: "memory");
      __builtin_amdgcn_sched_barrier(0);
      if (l == 0)
        __hip_atomic_store(myflag, t + 1, __ATOMIC_RELAXED,
                           __HIP_MEMORY_SCOPE_AGENT);
      // off-critical-path: hs store (next GEMM) + PQ(t+1) prefetch.
      {
        u32x2 hd2;
        hd2[0] = d01;
        hd2[1] = d23;
        asm volatile("global_store_dwordx2 %0, %1, %2"
                     :: "v"(voffH), "v"(hd2), "s"(sH) : "memory");
      }
      if (t < 499) PQ_ISSUE();
    } else {
      u32x2 hd;
      hd[0] = d01;
      hd[1] = d23;
      asm volatile("global_store_dwordx2 %0, %1, %2"
                   :: "v"(voffT), "v"(hd), "s"(sT) : "memory");
      asm volatile("s_waitcnt vmcnt(0)" ::: "memory");
      __threadfence();
      if (l == 0)
        __hip_atomic_store(myflag, t + 1, __ATOMIC_RELEASE,
                           __HIP_MEMORY_SCOPE_AGENT);
      {
        u32x2 hd2;
        hd2[0] = d01;
        hd2[1] = d23;
        asm volatile("global_store_dwordx2 %0, %1, %2"
                     :: "v"(voffH), "v"(hd2), "s"(sH) : "memory");
      }
      if (t < 499) PQ_ISSUE();
    }
    sH += 1024;
    sP1 += dP1;
    sP2 -= 2048;
  }
#undef PQ_ISSUE
}

// 256 one-wave blocks: bid = ws*8 + rg (rg-siblings co-XCD under %8 dispatch,
// verified at runtime via HW_REG_XCC_ID; else fenced fallback).
template <int PAIRED>
__global__ __launch_bounds__(64, 1) void k_scan(
    const unsigned short* __restrict__ Ub,  // [1024][512] bf16
    const unsigned short* __restrict__ PQ,  // bf16 projections
    unsigned short* __restrict__ hs,        // [128][500][512] bf16
    unsigned short* __restrict__ hx,        // exchange ring, 4*8*32*256 bf16
    int* __restrict__ flags,                // [8 rg][64]
    int* __restrict__ xcc) {                // [8 rg][64]
  const int bid = blockIdx.x;
  const int rg = bid & 7, ws = bid >> 3;
  const int l = threadIdx.x;
  const int l15 = l & 15, l4 = l >> 4, pl = l & 31;

  int myxcc;
  asm volatile("s_getreg_b32 %0, hwreg(HW_REG_XCC_ID)" : "=s"(myxcc));
  myxcc &= 0xff;
  if (l == 0)
    __hip_atomic_store(xcc + rg * 64 + ws, myxcc + 1, __ATOMIC_RELEASE,
                       __HIP_MEMORY_SCOPE_AGENT);

  // ---- U fragments resident in VGPRs: lane l15 = gate-col 16*ws+l15 ----
  bf16x8 Ua[16], Uz[16];
  {
    const int ja = 16 * ws + l15;
    const unsigned short* pa = Ub + ja * 512 + 8 * l4;
    const unsigned short* pz = pa + 512 * 512;
#pragma unroll
    for (int kt = 0; kt < 16; ++kt) {
      Ua[kt] = *(const bf16x8*)(pa + kt * 32);
      Uz[kt] = *(const bf16x8*)(pz + kt * 32);
    }
  }

  bool fast;
  {
    int v;
    for (;;) {
      v = __hip_atomic_load(xcc + rg * 64 + pl, __ATOMIC_ACQUIRE,
                            __HIP_MEMORY_SCOPE_AGENT);
      if (__all(v != 0)) break;
      __builtin_amdgcn_s_sleep(1);
    }
    fast = __all(v == myxcc + 1);
  }

  int* myflag = flags + rg * 64 + ws;
  int* rgflags = flags + rg * 64;
  if (fast)
    scan_body<PAIRED, true>(rg, ws, l, l15, l4, pl, Ua, Uz, PQ, hs, hx, rgflags, myflag);
  else
    scan_body<PAIRED, false>(rg, ws, l, l15, l4, pl, Ua, Uz, PQ, hs, hx, rgflags, myflag);
}

// ------------------------------ final combine -------------------------------
__global__ void k_combine(const float* __restrict__ Rf, const float* __restrict__ fcb,
                          const int* __restrict__ len32, float* __restrict__ out) {
  int i = blockIdx.x * 256 + threadIdx.x;
  if (i >= 64 * 500 * 61) return;
  const int o = i % 61;
  const int bt = i / 61;
  const int t = bt % 500;
  const int b = bt / 500;
  const bool is64 = (len32[1] == 0);
  const int L = is64 ? len32[2 * b] : len32[b];
  float v = 0.f;
  if (t < L) {
    v = Rf[((long)(b * 500 + t)) * 128 + o] +
        Rf[((long)((b + 64) * 500 + (499 - t))) * 128 + 61 + o] + fcb[o];
  }
  out[i] = v;
}

// ----------------------------------------------------------------------------
extern "C" void kernel_launch(void* const* d_in, const int* in_sizes, int n_in,
                              void* d_out, int out_size, void* d_ws, size_t ws_size,
                              hipStream_t stream) {
  (void)in_sizes; (void)n_in; (void)out_size; (void)ws_size;
  const float* x = (const float*)d_in[0];
  const int* len32 = (const int*)d_in[1];
  const float* W0 = (const float*)d_in[2];
  const float* U0 = (const float*)d_in[3];
  const float* W1 = (const float*)d_in[4];
  const float* U1 = (const float*)d_in[5];
  const float* W2 = (const float*)d_in[6];
  const float* U2 = (const float*)d_in[7];
  const float* fcw = (const float*)d_in[8];
  const float* fcb = (const float*)d_in[9];
  float* out = (float*)d_out;

  char* ws = (char*)d_ws;
  size_t off = 0;
  auto alloc = [&](size_t bytes) -> void* {
    void* p = ws + off;
    off = (off + bytes + 255) & ~(size_t)255;
    return p;
  };
  unsigned short* hs   = (unsigned short*)alloc(128ull * 500 * 512 * 2);
  unsigned short* PQ   = (unsigned short*)alloc(128ull * 500 * 1024 * 2);
  float*          Rf   = (float*)PQ;  // alias: PQ dead by FC time
  unsigned short* xb   = (unsigned short*)alloc(32000ull * 96 * 2);
  unsigned short* W0b  = (unsigned short*)alloc(1024ull * 96 * 2);
  unsigned short* WaT1 = (unsigned short*)alloc(1024ull * 512 * 2);
  unsigned short* WbT1 = (unsigned short*)alloc(1024ull * 512 * 2);
  unsigned short* WaT2 = (unsigned short*)alloc(1024ull * 512 * 2);
  unsigned short* WbT2 = (unsigned short*)alloc(1024ull * 512 * 2);
  unsigned short* Ub0  = (unsigned short*)alloc(1024ull * 512 * 2);
  unsigned short* Ub1  = (unsigned short*)alloc(1024ull * 512 * 2);
  unsigned short* Ub2  = (unsigned short*)alloc(1024ull * 512 * 2);
  unsigned short* fcT  = (unsigned short*)alloc(128ull * 512 * 2);
  unsigned short* hx   = (unsigned short*)alloc(4ull * 8 * 32 * 256 * 2);
  int*            bar  = (int*)alloc(3 * 1024 * 4);

  k_init<<<1, 256, 0, stream>>>(bar, fcT + 122 * 512);
  k_f2b<<<32000, 128, 0, stream>>>(xb, x, 96, 89, 0, 89);
  k_f2b<<<1024, 128, 0, stream>>>(W0b, W0, 96, 89, 0, 89);
  k_f2b<<<1024, 128, 0, stream>>>(WaT1, W1, 512, 1024, 0, 512);
  k_f2b<<<1024, 128, 0, stream>>>(WbT1, W1, 512, 1024, 512, 512);
  k_f2b<<<1024, 128, 0, stream>>>(WaT2, W2, 512, 1024, 0, 512);
  k_f2b<<<1024, 128, 0, stream>>>(WbT2, W2, 512, 1024, 512, 512);
  k_f2b<<<1024, 128, 0, stream>>>(Ub0, U0, 512, 512, 0, 512);
  k_f2b<<<1024, 128, 0, stream>>>(Ub1, U1, 512, 512, 0, 512);
  k_f2b<<<1024, 128, 0, stream>>>(Ub2, U2, 512, 512, 0, 512);
  k_f2b<<<61, 128, 0, stream>>>(fcT, fcw, 512, 1024, 0, 512);
  k_f2b<<<61, 128, 0, stream>>>(fcT + 61 * 512, fcw, 512, 1024, 512, 512);

  // layer 0
  k_gemm<1><<<dim3(250, 8), 256, 0, stream>>>(xb, W0b, PQ, 96, 1024);
  k_scan<0><<<256, 64, 0, stream>>>(Ub0, PQ, hs, hx, bar + 0, bar + 512);
  // layer 1
  k_gemm<1><<<dim3(250, 8), 256, 0, stream>>>(hs, WaT1, PQ, 512, 1024);
  k_gemm<1><<<dim3(250, 8), 256, 0, stream>>>(hs + 32000ull * 512, WbT1,
                                              PQ + 32000ull * 1024, 512, 1024);
  k_scan<1><<<256, 64, 0, stream>>>(Ub1, PQ, hs, hx, bar + 1024, bar + 1536);
  // layer 2
  k_gemm<1><<<dim3(250, 8), 256, 0, stream>>>(hs, WaT2, PQ, 512, 1024);
  k_gemm<1><<<dim3(250, 8), 256, 0, stream>>>(hs + 32000ull * 512, WbT2,
                                              PQ + 32000ull * 1024, 512, 1024);
  k_scan<1><<<256, 64, 0, stream>>>(Ub2, PQ, hs, hx, bar + 2048, bar + 2560);
  // final FC + combine/mask
  k_gemm<0><<<dim3(500, 1), 256, 0, stream>>>(hs, fcT, Rf, 512, 128);
  k_combine<<<(64 * 500 * 61 + 255) / 256, 256, 0, stream>>>(Rf, fcb, len32, out);
}